// Round 15
// baseline (1550.204 us; speedup 1.0000x reference)
//
#include <hip/hip_runtime.h>

#define N_NODES 100000
#define N_EDGES 1600000
#define D 128
#define N_STRIPS (N_NODES / 32)     // 3125

#define BSH   8                     // bucket = col >> 8 (256 nodes/bucket)
#define NBKT  391                   // ceil(100000 / 256)
#define P_BLK 512                   // scatter blocks; EPB = 3125 exactly
#define EPB   (N_EDGES / P_BLK)
#define ARENA 5120                  // per-bucket arena slots (mean 4092 + ~16 sigma)

typedef __bf16 bf16x4 __attribute__((ext_vector_type(4)));
typedef __bf16 bf16x8 __attribute__((ext_vector_type(8)));
typedef float  f32x4  __attribute__((ext_vector_type(4)));

// ---- K1: self-reserving coalesced scatter (1024 thr, 2 blocks/CU).
// LDS-sort the 3125-edge slice by bucket, reserve one arena window per bucket
// (single global atomicAdd), write bucket-runs coalesced. rec = row<<8 | col&255.
// Block P_BLK casts W -> bf16. ----
__global__ __launch_bounds__(1024) void k_scatter(const int* __restrict__ row,
                                                  const int* __restrict__ col,
                                                  const float4* __restrict__ w4,
                                                  int* __restrict__ gcnt,
                                                  unsigned* __restrict__ arena,
                                                  bf16x4* __restrict__ wb4) {
    int b = blockIdx.x, t = threadIdx.x;
    if (b == P_BLK) {                      // cast W -> bf16 (4096 float4)
        for (int i = t; i < (D * D) / 4; i += 1024) {
            float4 u = w4[i];
            bf16x4 p;
            p[0] = (__bf16)u.x; p[1] = (__bf16)u.y;
            p[2] = (__bf16)u.z; p[3] = (__bf16)u.w;
            wb4[i] = p;
        }
        return;
    }
    __shared__ int      rec[EPB];          // packed (row<<8 | col&255)
    __shared__ unsigned short kb[EPB];     // bucket id per edge
    __shared__ int      srt[EPB];          // bucket-sorted records
    __shared__ int      dofp[EPB];         // per-record global offset delta
    __shared__ int      lh[512];           // local hist
    __shared__ int      sc[512];           // exclusive scan
    __shared__ int      cur[512];          // placement cursors
    __shared__ int      dofk[512];         // per-bucket dst delta
    if (t < 512) lh[t] = 0;
    __syncthreads();
    int e0 = b * EPB;
    for (int i = t; i < EPB; i += 1024) {
        int r = row[e0 + i], c = col[e0 + i];
        int k = c >> BSH;
        rec[i] = (r << BSH) | (c & ((1 << BSH) - 1));
        kb[i]  = (unsigned short)k;
        atomicAdd(&lh[k], 1);
    }
    __syncthreads();
    int v = 0;
    if (t < 512) { v = lh[t]; sc[t] = v; }
    __syncthreads();
    for (int off = 1; off < 512; off <<= 1) {
        int u = 0;
        if (t < 512 && t >= off) u = sc[t - off];
        __syncthreads();
        if (t < 512) sc[t] += u;
        __syncthreads();
    }
    if (t < 512) {
        int excl = sc[t] - v;              // local exclusive base
        sc[t]  = excl;
        cur[t] = 0;
        int base = (t < NBKT && v > 0) ? atomicAdd(&gcnt[t], v) : 0;
        dofk[t] = t * ARENA + base - excl; // global dst = local pos + dofk
    }
    __syncthreads();
    for (int i = t; i < EPB; i += 1024) {
        int k = kb[i];
        int p = sc[k] + atomicAdd(&cur[k], 1);
        srt[p]  = rec[i];
        dofp[p] = dofk[k];
    }
    __syncthreads();
    for (int i = t; i < EPB; i += 1024) {
        unsigned dst = (unsigned)(i + dofp[i]);
        if (dst < (unsigned)(NBKT * ARENA))         // defensive
            arena[dst] = (unsigned)srt[i];
    }
}

// ---- K2: per-bucket degree histogram -> dis only (no sort, no placement) ----
__global__ __launch_bounds__(256) void k_deg(const unsigned* __restrict__ arena,
                                             const int* __restrict__ gcnt,
                                             float* __restrict__ dis) {
    __shared__ int h[256];
    int b = blockIdx.x, t = threadIdx.x;
    int cnt = gcnt[b]; if (cnt > ARENA) cnt = ARENA;
    int gs = b * ARENA;
    h[t] = 0;
    __syncthreads();
    for (int i = t; i < cnt; i += 256)
        atomicAdd(&h[arena[gs + i] & 255], 1);
    __syncthreads();
    int node = (b << BSH) + t;
    if (node < N_NODES)
        dis[node] = rsqrtf((float)h[t] + 1.0f);
}

// ---- K3: transform-first: hb[row] = bf16( (x @ W^T)[row] * dis[row] ) ----
__global__ __launch_bounds__(256) void k_hx(const float* __restrict__ x,
                                            const __bf16* __restrict__ wb,
                                            const float* __restrict__ dis,
                                            __bf16* __restrict__ hb) {
    int wave = threadIdx.x >> 6;
    int lane = threadIdx.x & 63;
    int strip = blockIdx.x * 4 + wave;
    if (strip >= N_STRIPS) return;
    int m0 = strip * 32;
    int l15 = lane & 15;
    int kq  = lane >> 4;

    bf16x8 a[2][4];
    #pragma unroll
    for (int mt = 0; mt < 2; ++mt) {
        const float* ap = x + (size_t)(m0 + mt * 16 + l15) * D + kq * 8;
        #pragma unroll
        for (int ks = 0; ks < 4; ++ks) {
            float4 lo = *(const float4*)(ap + ks * 32);
            float4 hi = *(const float4*)(ap + ks * 32 + 4);
            bf16x8 t;
            t[0] = (__bf16)lo.x; t[1] = (__bf16)lo.y;
            t[2] = (__bf16)lo.z; t[3] = (__bf16)lo.w;
            t[4] = (__bf16)hi.x; t[5] = (__bf16)hi.y;
            t[6] = (__bf16)hi.z; t[7] = (__bf16)hi.w;
            a[mt][ks] = t;
        }
    }

    f32x4 acc[2][8] = {};
    #pragma unroll
    for (int ks = 0; ks < 4; ++ks) {
        #pragma unroll
        for (int nt = 0; nt < 8; ++nt) {
            bf16x8 b = *(const bf16x8*)(wb + (size_t)(nt * 16 + l15) * D + ks * 32 + kq * 8);
            acc[0][nt] = __builtin_amdgcn_mfma_f32_16x16x32_bf16(a[0][ks], b, acc[0][nt], 0, 0, 0);
            acc[1][nt] = __builtin_amdgcn_mfma_f32_16x16x32_bf16(a[1][ks], b, acc[1][nt], 0, 0, 0);
        }
    }

    float dsv[2][4];
    #pragma unroll
    for (int mt = 0; mt < 2; ++mt)
        #pragma unroll
        for (int r = 0; r < 4; ++r)
            dsv[mt][r] = dis[m0 + mt * 16 + kq * 4 + r];

    #pragma unroll
    for (int nt = 0; nt < 8; ++nt) {
        int colj = nt * 16 + l15;
        #pragma unroll
        for (int mt = 0; mt < 2; ++mt) {
            #pragma unroll
            for (int r = 0; r < 4; ++r) {
                int rowi = m0 + mt * 16 + kq * 4 + r;
                hb[(size_t)rowi * D + colj] = (__bf16)(acc[mt][nt][r] * dsv[mt][r]);
            }
        }
    }
}

// ---- K4: bucket-aggregate. One block per 256-node bucket; output tile kept
// in LDS as f32 (256 x 128 = 128 KB dynamic). Stream the bucket's coarse
// records: broadcast row, 64 lanes read the 256B prescaled hb row, ds_add
// into acc[cl]. Epilogue: out = dc*(acc + hb_self) + bias, relu. ----
__global__ __launch_bounds__(1024) void k_bagg(const unsigned* __restrict__ arena,
                                               const int* __restrict__ gcnt,
                                               const __bf16* __restrict__ hb,
                                               const float* __restrict__ dis,
                                               const float* __restrict__ bias,
                                               float* __restrict__ out) {
    extern __shared__ float acc[];             // [256 * 128] = 131072 B
    int b = blockIdx.x, t = threadIdx.x;
    int cnt = gcnt[b]; if (cnt > ARENA) cnt = ARENA;
    int gs = b * ARENA;
    int node0 = b << BSH;
    const unsigned char* hbase = (const unsigned char*)hb;
    int wid  = t >> 6;
    int lane = t & 63;

    for (int i = t; i < 256 * 128; i += 1024) acc[i] = 0.f;
    __syncthreads();

    for (int base = wid * 64; base < cnt; base += 1024) {   // 16 waves x 64
        int m = cnt - base; if (m > 64) m = 64;
        unsigned rec_l = (lane < m) ? arena[gs + base + lane] : 0u;
        int j = 0;
        for (; j + 4 <= m; j += 4) {
            unsigned rj[4]; unsigned vj[4];
            #pragma unroll
            for (int k = 0; k < 4; ++k)
                rj[k] = __shfl(rec_l, j + k);
            #pragma unroll
            for (int k = 0; k < 4; ++k)
                vj[k] = *(const unsigned*)(hbase + (size_t)(rj[k] & ~255u) + lane * 4);
            #pragma unroll
            for (int k = 0; k < 4; ++k) {
                int cl = (int)(rj[k] & 255u);
                atomicAdd(&acc[cl * 128 + lane * 2],     __uint_as_float(vj[k] << 16));
                atomicAdd(&acc[cl * 128 + lane * 2 + 1], __uint_as_float(vj[k] & 0xFFFF0000u));
            }
        }
        for (; j < m; ++j) {
            unsigned rj = __shfl(rec_l, j);
            unsigned v = *(const unsigned*)(hbase + (size_t)(rj & ~255u) + lane * 4);
            int cl = (int)(rj & 255u);
            atomicAdd(&acc[cl * 128 + lane * 2],     __uint_as_float(v << 16));
            atomicAdd(&acc[cl * 128 + lane * 2 + 1], __uint_as_float(v & 0xFFFF0000u));
        }
    }
    __syncthreads();

    // epilogue: thread t -> node t>>2, col group (t&3)*32 .. +31
    int nd = node0 + (t >> 2);
    if (nd < N_NODES) {
        int g = (t & 3) * 32;                  // starting col
        float dc = dis[nd];
        const float* ac = acc + (size_t)(t >> 2) * 128 + g;
        const unsigned* selfp = (const unsigned*)(hbase + (size_t)nd * 256 + g * 2);
        float* op = out + (size_t)nd * D + g;
        #pragma unroll
        for (int j8 = 0; j8 < 4; ++j8) {       // 4 x 8 cols
            uint4 sv = *(const uint4*)(selfp + j8 * 4);
            float s[8];
            s[0] = __uint_as_float(sv.x << 16); s[1] = __uint_as_float(sv.x & 0xFFFF0000u);
            s[2] = __uint_as_float(sv.y << 16); s[3] = __uint_as_float(sv.y & 0xFFFF0000u);
            s[4] = __uint_as_float(sv.z << 16); s[5] = __uint_as_float(sv.z & 0xFFFF0000u);
            s[6] = __uint_as_float(sv.w << 16); s[7] = __uint_as_float(sv.w & 0xFFFF0000u);
            float4 r0, r1;
            const float* b0 = bias + g + j8 * 8;
            r0.x = fmaxf((ac[j8*8+0] + s[0]) * dc + b0[0], 0.f);
            r0.y = fmaxf((ac[j8*8+1] + s[1]) * dc + b0[1], 0.f);
            r0.z = fmaxf((ac[j8*8+2] + s[2]) * dc + b0[2], 0.f);
            r0.w = fmaxf((ac[j8*8+3] + s[3]) * dc + b0[3], 0.f);
            r1.x = fmaxf((ac[j8*8+4] + s[4]) * dc + b0[4], 0.f);
            r1.y = fmaxf((ac[j8*8+5] + s[5]) * dc + b0[5], 0.f);
            r1.z = fmaxf((ac[j8*8+6] + s[6]) * dc + b0[6], 0.f);
            r1.w = fmaxf((ac[j8*8+7] + s[7]) * dc + b0[7], 0.f);
            *(float4*)(op + j8 * 8)     = r0;
            *(float4*)(op + j8 * 8 + 4) = r1;
        }
    }
}

extern "C" void kernel_launch(void* const* d_in, const int* in_sizes, int n_in,
                              void* d_out, int out_size, void* d_ws, size_t ws_size,
                              hipStream_t stream) {
    const float* x    = (const float*)d_in[0];
    const int*   ei   = (const int*)d_in[1];    // [2, E]: row then col
    const float* w    = (const float*)d_in[2];
    const float* bias = (const float*)d_in[3];
    float* out = (float*)d_out;

    char* ws = (char*)d_ws;
    float*    dis    = (float*)ws;            ws += N_NODES * 4;
    int*      gcnt   = (int*)ws;              ws += 512 * 4;
    __bf16*   wb     = (__bf16*)ws;           ws += D * D * 2;
    unsigned* arena  = (unsigned*)ws;         ws += (size_t)NBKT * ARENA * 4;
    __bf16*   hb     = (__bf16*)ws;           // N_NODES * D * 2 = 25.6 MB

    const int* row = ei;
    const int* col = ei + N_EDGES;

    hipMemsetAsync(gcnt, 0, 512 * 4, stream);
    k_scatter<<<P_BLK + 1, 1024, 0, stream>>>(row, col, (const float4*)w, gcnt, arena, (bf16x4*)wb);
    k_deg    <<<NBKT, 256, 0, stream>>>(arena, gcnt, dis);
    k_hx     <<<(N_STRIPS + 3) / 4, 256, 0, stream>>>(x, wb, dis, hb);
    k_bagg   <<<NBKT, 1024, 131072, stream>>>(arena, gcnt, hb, dis, bias, out);
}